// Round 1
// baseline (382.381 us; speedup 1.0000x reference)
//
#include <hip/hip_runtime.h>
#include <hip/hip_bf16.h>

#define KK 32
#define DIN 128
#define DOUT 32
#define NVEC (KK * DOUT)        // 1024 floats per node
#define NV4  (NVEC / 4)         // 256 float4 per node

// bf16 bits -> float
__device__ __forceinline__ float bfu2f(unsigned int u) {
    return __uint_as_float(u << 16);
}
__device__ __forceinline__ unsigned int f2bfu(float f) {
    __hip_bfloat16 b = __float2bfloat16(f);
    return *(unsigned short*)&b;
}

// ---------------- K1: h[r][e] = sum_d x[r][d] * W[d][e], store bf16 ----------
// R = N*K rows. Block = 256 threads; each thread computes 4 output cols of one
// row (eg = tid&7 selects col group, tid>>3 selects row within block's 32 rows).
__global__ __launch_bounds__(256) void gemm_kernel(
    const float* __restrict__ x, const float* __restrict__ w,
    unsigned short* __restrict__ h, int R)
{
    __shared__ float wlds[DIN * DOUT];   // 16 KB
    const int tid = threadIdx.x;
    // cooperative W load, float4
    const float4* w4 = (const float4*)w;
    float4* wl4 = (float4*)wlds;
    #pragma unroll
    for (int i = tid; i < DIN * DOUT / 4; i += 256) wl4[i] = w4[i];
    __syncthreads();

    const int r  = blockIdx.x * 32 + (tid >> 3);
    const int eg = tid & 7;
    if (r >= R) return;

    const float4* x4 = (const float4*)(x + (size_t)r * DIN);
    float ax = 0.f, ay = 0.f, az = 0.f, aw = 0.f;
    #pragma unroll 4
    for (int d4 = 0; d4 < DIN / 4; ++d4) {
        float4 xv = x4[d4];
        float4 w0 = wl4[(d4 * 4 + 0) * 8 + eg];
        float4 w1 = wl4[(d4 * 4 + 1) * 8 + eg];
        float4 w2 = wl4[(d4 * 4 + 2) * 8 + eg];
        float4 w3 = wl4[(d4 * 4 + 3) * 8 + eg];
        ax += xv.x * w0.x + xv.y * w1.x + xv.z * w2.x + xv.w * w3.x;
        ay += xv.x * w0.y + xv.y * w1.y + xv.z * w2.y + xv.w * w3.y;
        az += xv.x * w0.z + xv.y * w1.z + xv.z * w2.z + xv.w * w3.z;
        aw += xv.x * w0.w + xv.y * w1.w + xv.z * w2.w + xv.w * w3.w;
    }
    uint2 packed;
    packed.x = f2bfu(ax) | (f2bfu(ay) << 16);
    packed.y = f2bfu(az) | (f2bfu(aw) << 16);
    *(uint2*)(h + (size_t)r * DOUT + eg * 4) = packed;
}

// ---------------- K2: zero int array ----------------------------------------
__global__ void zero_kernel(int* __restrict__ p, int n) {
    int i = blockIdx.x * 256 + threadIdx.x;
    if (i < n) p[i] = 0;
}

// ---------------- K3: histogram of destination rows -------------------------
__global__ void hist_kernel(const int* __restrict__ row, int* __restrict__ counts, int E) {
    int i = blockIdx.x * 256 + threadIdx.x;
    if (i < E) atomicAdd(&counts[row[i]], 1);
}

// ---------------- K4: single-block exclusive scan ---------------------------
// counts (== cursor array) -> offsets[0..n] ; cursor reset to start positions.
__global__ __launch_bounds__(256) void scan_kernel(
    int* __restrict__ counts_cursor, int* __restrict__ offsets, int n)
{
    __shared__ int buf[256];
    __shared__ int carry;
    const int tid = threadIdx.x;
    if (tid == 0) carry = 0;
    __syncthreads();
    for (int base = 0; base < n; base += 256) {
        int i = base + tid;
        int v = (i < n) ? counts_cursor[i] : 0;
        buf[tid] = v;
        __syncthreads();
        #pragma unroll
        for (int off = 1; off < 256; off <<= 1) {
            int t = (tid >= off) ? buf[tid - off] : 0;
            __syncthreads();
            buf[tid] += t;
            __syncthreads();
        }
        int excl = buf[tid] - v;
        if (i < n) {
            int start = carry + excl;
            offsets[i] = start;
            counts_cursor[i] = start;   // cursor for fill pass
        }
        __syncthreads();
        if (tid == 255) carry += buf[255];
        __syncthreads();
    }
    if (tid == 0) offsets[n] = carry;
}

// ---------------- K5: scatter edges into CSR order --------------------------
__global__ void fill_kernel(const int* __restrict__ row, const int* __restrict__ col,
                            const float* __restrict__ val, int* __restrict__ cursor,
                            int* __restrict__ scol, float* __restrict__ sval, int E)
{
    int i = blockIdx.x * 256 + threadIdx.x;
    if (i < E) {
        int p = atomicAdd(&cursor[row[i]], 1);
        scol[p] = col[i];
        sval[p] = val[i];
    }
}

// ---------------- K6: per-node gather-accumulate + ReLU ----------------------
// One block per node; thread owns 4 consecutive floats of the 1024-vector.
__global__ __launch_bounds__(256) void agg_kernel(
    const unsigned short* __restrict__ h, const int* __restrict__ offsets,
    const int* __restrict__ scol, const float* __restrict__ sval,
    float* __restrict__ out)
{
    const int r   = blockIdx.x;
    const int tid = threadIdx.x;
    const int beg = offsets[r];
    const int end = offsets[r + 1];

    float ax = 0.f, ay = 0.f, az = 0.f, aw = 0.f;
    for (int j = beg; j < end; ++j) {
        int   c = scol[j];
        float v = sval[j];
        uint2 p = *(const uint2*)(h + (size_t)c * NVEC + tid * 4);
        ax += v * bfu2f(p.x & 0xffffu);
        ay += v * bfu2f(p.x >> 16);
        az += v * bfu2f(p.y & 0xffffu);
        aw += v * bfu2f(p.y >> 16);
    }
    float4 o;
    o.x = fmaxf(ax, 0.f);
    o.y = fmaxf(ay, 0.f);
    o.z = fmaxf(az, 0.f);
    o.w = fmaxf(aw, 0.f);
    ((float4*)out)[(size_t)r * NV4 + tid] = o;
}

extern "C" void kernel_launch(void* const* d_in, const int* in_sizes, int n_in,
                              void* d_out, int out_size, void* d_ws, size_t ws_size,
                              hipStream_t stream)
{
    const float* x    = (const float*)d_in[0];
    const float* w    = (const float*)d_in[1];
    const int*   erow = (const int*)d_in[2];
    const int*   ecol = (const int*)d_in[3];
    const float* eval = (const float*)d_in[4];
    float* out = (float*)d_out;

    const int E = in_sizes[2];
    const int N = in_sizes[0] / (KK * DIN);
    const int R = N * KK;

    // workspace carve-up (16B aligned slices)
    char* ws = (char*)d_ws;
    size_t off = 0;
    auto take = [&](size_t bytes) {
        void* p = ws + off;
        off += (bytes + 15) & ~(size_t)15;
        return p;
    };
    unsigned short* h = (unsigned short*)take((size_t)R * DOUT * sizeof(unsigned short));
    int*   offsets = (int*)take((size_t)(N + 1) * sizeof(int));
    int*   cursor  = (int*)take((size_t)N * sizeof(int));
    int*   scol    = (int*)take((size_t)E * sizeof(int));
    float* sval    = (float*)take((size_t)E * sizeof(float));
    (void)ws_size;

    gemm_kernel<<<(R + 31) / 32, 256, 0, stream>>>(x, w, h, R);
    zero_kernel<<<(N + 255) / 256, 256, 0, stream>>>(cursor, N);
    hist_kernel<<<(E + 255) / 256, 256, 0, stream>>>(erow, cursor, E);
    scan_kernel<<<1, 256, 0, stream>>>(cursor, offsets, N);
    fill_kernel<<<(E + 255) / 256, 256, 0, stream>>>(erow, ecol, eval, cursor, scol, sval, E);
    agg_kernel<<<N, 256, 0, stream>>>(h, offsets, scol, sval, out);
}

// Round 2
// 365.592 us; speedup vs baseline: 1.0459x; 1.0459x over previous
//
#include <hip/hip_runtime.h>
#include <hip/hip_bf16.h>

#define KK 32
#define DIN 128
#define DOUT 32
#define NVEC (KK * DOUT)        // 1024 floats per node
#define NV4  (NVEC / 4)         // 256 float4 per node

__device__ __forceinline__ float bfu2f(unsigned int u) {
    return __uint_as_float(u << 16);
}
__device__ __forceinline__ unsigned int f2bfu(float f) {
    __hip_bfloat16 b = __float2bfloat16(f);
    return *(unsigned short*)&b;
}

// ---------------- K1: h[r][e] = sum_d x[r][d] * W[d][e], store bf16 ----------
// Each thread: 4 rows x 4 cols. Block=256 -> 128 rows/block. R=320000 -> grid 2500.
// LDS W-slice reads amortized over 4 rows (5.1 GB -> 1.3 GB total LDS traffic).
__global__ __launch_bounds__(256) void gemm_kernel(
    const float* __restrict__ x, const float* __restrict__ w,
    unsigned short* __restrict__ h)
{
    __shared__ float wlds[DIN * DOUT];   // 16 KB
    const int tid = threadIdx.x;
    const float4* w4 = (const float4*)w;
    float4* wl4 = (float4*)wlds;
    #pragma unroll
    for (int i = tid; i < DIN * DOUT / 4; i += 256) wl4[i] = w4[i];
    __syncthreads();

    const int eg = tid & 7;          // 4-col group
    const int rg = tid >> 3;         // 32 row-groups
    const int r0 = blockIdx.x * 128 + rg * 4;

    const float4* x0 = (const float4*)(x + (size_t)r0 * DIN);  // 4 rows, 32 f4 each
    float acc[4][4];
    #pragma unroll
    for (int a = 0; a < 4; ++a)
        #pragma unroll
        for (int b = 0; b < 4; ++b) acc[a][b] = 0.f;

    #pragma unroll 2
    for (int d4 = 0; d4 < DIN / 4; ++d4) {
        float4 wv0 = wl4[(d4 * 4 + 0) * 8 + eg];
        float4 wv1 = wl4[(d4 * 4 + 1) * 8 + eg];
        float4 wv2 = wl4[(d4 * 4 + 2) * 8 + eg];
        float4 wv3 = wl4[(d4 * 4 + 3) * 8 + eg];
        #pragma unroll
        for (int rr = 0; rr < 4; ++rr) {
            float4 xv = x0[rr * (DIN / 4) + d4];
            acc[rr][0] += xv.x * wv0.x + xv.y * wv1.x + xv.z * wv2.x + xv.w * wv3.x;
            acc[rr][1] += xv.x * wv0.y + xv.y * wv1.y + xv.z * wv2.y + xv.w * wv3.y;
            acc[rr][2] += xv.x * wv0.z + xv.y * wv1.z + xv.z * wv2.z + xv.w * wv3.z;
            acc[rr][3] += xv.x * wv0.w + xv.y * wv1.w + xv.z * wv2.w + xv.w * wv3.w;
        }
    }
    #pragma unroll
    for (int rr = 0; rr < 4; ++rr) {
        uint2 packed;
        packed.x = f2bfu(acc[rr][0]) | (f2bfu(acc[rr][1]) << 16);
        packed.y = f2bfu(acc[rr][2]) | (f2bfu(acc[rr][3]) << 16);
        *(uint2*)(h + (size_t)(r0 + rr) * DOUT + eg * 4) = packed;
    }
}

// ---------------- K2: zero int array ----------------------------------------
__global__ void zero_kernel(int* __restrict__ p, int n) {
    int i = blockIdx.x * 256 + threadIdx.x;
    if (i < n) p[i] = 0;
}

// ---------------- K3: histogram of destination rows -------------------------
__global__ void hist_kernel(const int* __restrict__ row, int* __restrict__ counts, int E) {
    int i = blockIdx.x * 256 + threadIdx.x;
    if (i < E) atomicAdd(&counts[row[i]], 1);
}

// ---------------- K4: single-block exclusive scan (wave shfl) ----------------
__global__ __launch_bounds__(256) void scan_kernel(
    int* __restrict__ counts_cursor, int* __restrict__ offsets, int n)
{
    __shared__ int wsum[4];
    __shared__ int carry;
    const int tid  = threadIdx.x;
    const int lane = tid & 63;
    const int wid  = tid >> 6;
    if (tid == 0) carry = 0;
    __syncthreads();
    for (int base = 0; base < n; base += 256) {
        int i = base + tid;
        int v = (i < n) ? counts_cursor[i] : 0;
        int s = v;
        #pragma unroll
        for (int off = 1; off < 64; off <<= 1) {
            int t = __shfl_up(s, off, 64);
            if (lane >= off) s += t;
        }
        if (lane == 63) wsum[wid] = s;
        __syncthreads();
        int prefix = carry;
        #pragma unroll
        for (int ww = 0; ww < 4; ++ww)
            if (ww < wid) prefix += wsum[ww];
        if (i < n) {
            int start = prefix + s - v;   // exclusive
            offsets[i] = start;
            counts_cursor[i] = start;
        }
        __syncthreads();
        if (tid == 0) carry += wsum[0] + wsum[1] + wsum[2] + wsum[3];
        __syncthreads();
    }
    if (tid == 0) offsets[n] = carry;
}

// ---------------- K5: scatter edges into CSR order --------------------------
__global__ void fill_kernel(const int* __restrict__ row, const int* __restrict__ col,
                            const float* __restrict__ val, int* __restrict__ cursor,
                            int* __restrict__ scol, float* __restrict__ sval, int E)
{
    int i = blockIdx.x * 256 + threadIdx.x;
    if (i < E) {
        int p = atomicAdd(&cursor[row[i]], 1);
        scol[p] = col[i];
        sval[p] = val[i];
    }
}

// ---------------- K6: per-node gather-accumulate + ReLU ----------------------
// 2 nodes/block, 128 threads/node, uint4 (8 bf16 = 16B) per thread per edge.
// Depth-2 software pipeline: next edge's index + gather in flight while
// accumulating the current one.
__global__ __launch_bounds__(256) void agg_kernel(
    const unsigned short* __restrict__ h, const int* __restrict__ offsets,
    const int* __restrict__ scol, const float* __restrict__ sval,
    float* __restrict__ out)
{
    const int tid  = threadIdx.x;
    const int half = tid >> 7;
    const int lt   = tid & 127;          // owns 8 floats
    const int r    = blockIdx.x * 2 + half;

    const int beg = offsets[r];
    const int end = offsets[r + 1];

    float acc[8];
    #pragma unroll
    for (int q = 0; q < 8; ++q) acc[q] = 0.f;

    int j = beg;
    float v = 0.f;
    uint4 p = {0, 0, 0, 0};
    if (j < end) {
        int c = scol[j];
        v = sval[j];
        p = *(const uint4*)(h + (size_t)c * NVEC + lt * 8);
    }
    while (j < end) {
        uint4 pc = p;
        float vc = v;
        int jn = j + 1;
        if (jn < end) {
            int cn = scol[jn];
            v = sval[jn];
            p = *(const uint4*)(h + (size_t)cn * NVEC + lt * 8);
        }
        acc[0] += vc * bfu2f(pc.x & 0xffffu);
        acc[1] += vc * bfu2f(pc.x >> 16);
        acc[2] += vc * bfu2f(pc.y & 0xffffu);
        acc[3] += vc * bfu2f(pc.y >> 16);
        acc[4] += vc * bfu2f(pc.z & 0xffffu);
        acc[5] += vc * bfu2f(pc.z >> 16);
        acc[6] += vc * bfu2f(pc.w & 0xffffu);
        acc[7] += vc * bfu2f(pc.w >> 16);
        j = jn;
    }

    float4 o0, o1;
    o0.x = fmaxf(acc[0], 0.f); o0.y = fmaxf(acc[1], 0.f);
    o0.z = fmaxf(acc[2], 0.f); o0.w = fmaxf(acc[3], 0.f);
    o1.x = fmaxf(acc[4], 0.f); o1.y = fmaxf(acc[5], 0.f);
    o1.z = fmaxf(acc[6], 0.f); o1.w = fmaxf(acc[7], 0.f);
    float4* orow = (float4*)out + (size_t)r * NV4 + lt * 2;
    orow[0] = o0;
    orow[1] = o1;
}

extern "C" void kernel_launch(void* const* d_in, const int* in_sizes, int n_in,
                              void* d_out, int out_size, void* d_ws, size_t ws_size,
                              hipStream_t stream)
{
    const float* x    = (const float*)d_in[0];
    const float* w    = (const float*)d_in[1];
    const int*   erow = (const int*)d_in[2];
    const int*   ecol = (const int*)d_in[3];
    const float* eval = (const float*)d_in[4];
    float* out = (float*)d_out;

    const int E = in_sizes[2];
    const int N = in_sizes[0] / (KK * DIN);
    const int R = N * KK;

    char* ws = (char*)d_ws;
    size_t off = 0;
    auto take = [&](size_t bytes) {
        void* p = ws + off;
        off += (bytes + 15) & ~(size_t)15;
        return p;
    };
    unsigned short* h = (unsigned short*)take((size_t)R * DOUT * sizeof(unsigned short));
    int*   offsets = (int*)take((size_t)(N + 1) * sizeof(int));
    int*   cursor  = (int*)take((size_t)N * sizeof(int));
    int*   scol    = (int*)take((size_t)E * sizeof(int));
    float* sval    = (float*)take((size_t)E * sizeof(float));
    (void)ws_size;

    gemm_kernel<<<R / 128, 256, 0, stream>>>(x, w, h);
    zero_kernel<<<(N + 255) / 256, 256, 0, stream>>>(cursor, N);
    hist_kernel<<<(E + 255) / 256, 256, 0, stream>>>(erow, cursor, E);
    scan_kernel<<<1, 256, 0, stream>>>(cursor, offsets, N);
    fill_kernel<<<(E + 255) / 256, 256, 0, stream>>>(erow, ecol, eval, cursor, scol, sval, E);
    agg_kernel<<<N / 2, 256, 0, stream>>>(h, offsets, scol, sval, out);
}